// Round 2
// baseline (180.030 us; speedup 1.0000x reference)
//
#include <hip/hip_runtime.h>

// BERT lattice embedding: ragged segment mean-pool.
// hidden: [B,S,H] f32, word_ids: [B,S] i32 (non-decreasing per sample),
// out: [B,T,H] f32 with out[b,t,:] = mean of hidden[b,s,:] over s where
// word_ids[b,s]==t (zeros if no such s).
//
// v3: MLP fix. v1/v2 both sat at ~60 us / 27% HBM with one short-lived wave
// per output row: each wave had ~3 KB in flight for ~20% of its life ->
// Little's law gives exactly the measured ~2 TB/s. Since word_ids is sorted,
// the pieces of k consecutive words are ONE contiguous s-range. So:
//  - wave = 5 consecutive words, workgroup = 4 waves = 20 words of one b.
//  - grid = 64*20 = 1280 wgs = 5 wgs/CU -> all 20 waves/CU resident.
//  - per wg: stage word_ids row in LDS, 21 lane-PARALLEL binary searches give
//    every word boundary; each wave then STREAMS its contiguous ~6.4-row
//    input range with a rolling 1-row prefetch (loads never depend on the
//    ragged structure), keeping >=3 KB continuously in flight per wave.
//  - lane layout unchanged: lane i owns float4 {i, i+64, i+128} of the
//    768-float row; fully coalesced 16B/lane loads and stores.

#define BB 64
#define SS 512
#define HH 768
#define TT 400
#define TB 5                 // words per wave
#define WAVES 4              // waves per workgroup
#define WWG (TB * WAVES)     // words per workgroup = 20; TT % WWG == 0
#define WGB (TT / WWG)       // workgroups per sample = 20
#define NF4 (HH / 4)         // 192 float4 per row

__global__ __launch_bounds__(256) void bert_lattice_pool_kernel(
    const float* __restrict__ hidden,
    const int* __restrict__ word_ids,
    float* __restrict__ out)
{
    const int wg  = blockIdx.x;
    const int b   = wg / WGB;
    const int tw0 = (wg - b * WGB) * WWG;   // first word of this wg

    __shared__ int s_w[SS];
    __shared__ int s_bnd[WWG + 1];

    const int tid = threadIdx.x;

    // Stage the word_ids row: 512 ints = 256 int2, one per thread, coalesced.
    const int2* wrow2 = reinterpret_cast<const int2*>(word_ids + b * SS);
    reinterpret_cast<int2*>(s_w)[tid] = wrow2[tid];
    __syncthreads();

    // Lane-parallel bounds: thread i computes lower_bound(tw0 + i), i=0..20.
    // start(t) = s_bnd[t-tw0], end(t) = s_bnd[t-tw0+1].
    if (tid <= WWG) {
        const int t = tw0 + tid;
        int lo = 0, hi = SS;
        while (lo < hi) {
            const int mid = (lo + hi) >> 1;
            if (s_w[mid] < t) lo = mid + 1; else hi = mid;
        }
        s_bnd[tid] = lo;
    }
    __syncthreads();

    const int wv   = tid >> 6;    // wave 0..3
    const int lane = tid & 63;
    const int i0   = wv * TB;     // this wave's first bound index

    int s        = s_bnd[i0];         // stream position (contiguous!)
    const int S1 = s_bnd[i0 + TB];    // end of this wave's stream

    const float4* hbase = reinterpret_cast<const float4*>(hidden)
                          + (size_t)(b * SS) * NF4;

    // Rolling prefetch of the next stream row.
    float4 p0, p1, p2;
    if (s < S1) {
        const float4* p = hbase + (size_t)s * NF4;
        p0 = p[lane]; p1 = p[lane + 64]; p2 = p[lane + 128];
    }

    float4* obase = reinterpret_cast<float4*>(out)
                    + ((size_t)b * TT + tw0 + i0) * NF4;

    #pragma unroll
    for (int i = 0; i < TB; ++i) {
        const int e   = s_bnd[i0 + i + 1];
        const int cnt = e - s;
        float4 a0 = make_float4(0.f, 0.f, 0.f, 0.f);
        float4 a1 = a0, a2 = a0;
        while (s < e) {
            const float4 c0 = p0, c1 = p1, c2 = p2;
            const int sn = s + 1;
            if (sn < S1) {
                const float4* p = hbase + (size_t)sn * NF4;
                p0 = p[lane]; p1 = p[lane + 64]; p2 = p[lane + 128];
            }
            a0.x += c0.x; a0.y += c0.y; a0.z += c0.z; a0.w += c0.w;
            a1.x += c1.x; a1.y += c1.y; a1.z += c1.z; a1.w += c1.w;
            a2.x += c2.x; a2.y += c2.y; a2.z += c2.z; a2.w += c2.w;
            s = sn;
        }
        const float inv = 1.0f / (float)(cnt > 0 ? cnt : 1);
        float4* o = obase + (size_t)i * NF4;
        o[lane]       = make_float4(a0.x * inv, a0.y * inv, a0.z * inv, a0.w * inv);
        o[lane + 64]  = make_float4(a1.x * inv, a1.y * inv, a1.z * inv, a1.w * inv);
        o[lane + 128] = make_float4(a2.x * inv, a2.y * inv, a2.z * inv, a2.w * inv);
    }
}

extern "C" void kernel_launch(void* const* d_in, const int* in_sizes, int n_in,
                              void* d_out, int out_size, void* d_ws, size_t ws_size,
                              hipStream_t stream) {
    (void)in_sizes; (void)n_in; (void)d_ws; (void)ws_size; (void)out_size;
    const float* hidden   = (const float*)d_in[0];
    const int*   word_ids = (const int*)d_in[1];
    float*       out      = (float*)d_out;

    dim3 grid(BB * WGB);   // 1280 workgroups, 5 per CU
    dim3 block(256);
    bert_lattice_pool_kernel<<<grid, block, 0, stream>>>(hidden, word_ids, out);
}

// Round 4
// 178.031 us; speedup vs baseline: 1.0112x; 1.0112x over previous
//
#include <hip/hip_runtime.h>

// BERT lattice embedding: ragged segment mean-pool.
// hidden: [B,S,H] f32, word_ids: [B,S] i32 (non-decreasing per sample),
// out: [B,T,H] f32 with out[b,t,:] = mean of hidden[b,s,:] over s where
// word_ids[b,s]==t (zeros if no such s).
//
// v5 == v4 with the macro-shadowing bug fixed (PROC declared `const int r =
// (r)+i` when called with base=r -> self-initialized UB index). Structure:
//  - wave = one 256-float H-slice (1 float4/lane/row; 768 = 3 waves x 256).
//  - rows loaded in chunks of 8 INDEPENDENT global_load_dwordx4 with clamped
//    addresses, double-buffered A/B: next chunk issued before current is
//    consumed -> 8-16 KB continuously in flight per wave.
//  - word boundaries are wave-uniform registers; segment logic never
//    interrupts the load stream.
//  - bounds via O(1)-depth scatter scan of the staged word_ids row.
// Block = 192 threads = 3 waves sharing one 20-word range of one sample;
// grid = 64 * 20 = 1280 blocks.

#define BB 64
#define SS 512
#define HH 768
#define TT 400
#define NF4 (HH / 4)       // 192 float4 per row
#define W   20             // words per block; TT % W == 0
#define WGB (TT / W)       // blocks per sample = 20
#define NTHR 192           // 3 waves, one per 256-float H-slice
#define CH  8              // prefetch chunk depth (rows)

__global__ __launch_bounds__(NTHR) void bert_lattice_pool_kernel(
    const float* __restrict__ hidden,
    const int* __restrict__ word_ids,
    float* __restrict__ out)
{
    const int blk = blockIdx.x;
    const int b   = blk / WGB;
    const int w0  = (blk - b * WGB) * W;

    __shared__ int s_w[SS];
    __shared__ int s_bnd[W + 1];

    const int tid = threadIdx.x;

    // Stage word_ids row (512 ints = 256 int2) and init bounds to SS.
    const int2* wrow2 = reinterpret_cast<const int2*>(word_ids + b * SS);
    reinterpret_cast<int2*>(s_w)[tid] = wrow2[tid];
    if (tid < 64) reinterpret_cast<int2*>(s_w)[NTHR + tid] = wrow2[NTHR + tid];
    if (tid <= W) s_bnd[tid] = SS;
    __syncthreads();

    // Scatter lower bounds: for each s, words t with w[s-1] < t <= w[s] have
    // lower_bound(t) == s. Disjoint ranges -> conflict-free LDS writes.
    for (int s = tid; s < SS; s += NTHR) {
        const int w  = s_w[s];
        const int wp = (s == 0) ? -1 : s_w[s - 1];
        int lo = wp + 1; if (lo < w0) lo = w0;
        int hi = w;      if (hi > w0 + W) hi = w0 + W;
        for (int t = lo; t <= hi; ++t) s_bnd[t - w0] = s;
    }
    __syncthreads();

    const int wv   = tid >> 6;    // wave 0..2 -> H-slice
    const int lane = tid & 63;

    const int r0 = s_bnd[0];      // first input row of this block's words
    const int r1 = s_bnd[W];      // one past last

    const float4* hp = reinterpret_cast<const float4*>(hidden)
                       + (size_t)b * SS * NF4 + wv * 64 + lane;
    float4* op = reinterpret_cast<float4*>(out)
                 + ((size_t)b * TT + w0) * NF4 + wv * 64 + lane;

    const float4 z4 = make_float4(0.f, 0.f, 0.f, 0.f);

    // Flush leading zero-piece words (their lower bound equals r0).
    int t = 0;
    while (t < W && s_bnd[t + 1] == r0) { op[(size_t)t * NF4] = z4; ++t; }
    if (r0 >= r1) return;         // whole block empty; all words flushed

    int ws = r0;                              // current word's start row
    int e  = (t < W) ? s_bnd[t + 1] : -1;     // current word's end row
    float4 acc = z4;
    const int rmax = r1 - 1;

#define LOADC(Bufr, base)                                             \
    _Pragma("unroll")                                                 \
    for (int i = 0; i < CH; ++i) {                                    \
        int rr = (base) + i;                                          \
        rr = rr > rmax ? rmax : rr;      /* clamp: no branch, no OOB */ \
        Bufr[i] = hp[(size_t)rr * NF4];                               \
    }

#define PROC(Bufr, base)                                              \
    _Pragma("unroll")                                                 \
    for (int i = 0; i < CH; ++i) {                                    \
        const int rI = (base) + i;    /* unique name: no shadowing */ \
        if (rI < r1) {                                                \
            acc.x += Bufr[i].x; acc.y += Bufr[i].y;                   \
            acc.z += Bufr[i].z; acc.w += Bufr[i].w;                   \
            if (rI + 1 == e) {                                        \
                const int cnt = e - ws;                               \
                const float inv = 1.0f / (float)cnt;                  \
                op[(size_t)t * NF4] = make_float4(acc.x * inv,        \
                    acc.y * inv, acc.z * inv, acc.w * inv);           \
                acc = z4; ws = e; ++t;                                \
                while (t < W && s_bnd[t + 1] == e) {                  \
                    op[(size_t)t * NF4] = z4; ++t;   /* empty words */ \
                }                                                     \
                e = (t < W) ? s_bnd[t + 1] : -1;                      \
            }                                                         \
        }                                                             \
    }

    float4 A[CH], Bf[CH];
    int r = r0;
    LOADC(A, r);                  // prime the pipeline
    for (;;) {
        LOADC(Bf, r + CH);        // issue next chunk before consuming current
        PROC(A, r);
        r += CH;
        if (r >= r1) break;
        LOADC(A, r + CH);
        PROC(Bf, r);
        r += CH;
        if (r >= r1) break;
    }

#undef LOADC
#undef PROC
}

extern "C" void kernel_launch(void* const* d_in, const int* in_sizes, int n_in,
                              void* d_out, int out_size, void* d_ws, size_t ws_size,
                              hipStream_t stream) {
    (void)in_sizes; (void)n_in; (void)d_ws; (void)ws_size; (void)out_size;
    const float* hidden   = (const float*)d_in[0];
    const int*   word_ids = (const int*)d_in[1];
    float*       out      = (float*)d_out;

    dim3 grid(BB * WGB);    // 1280 blocks
    dim3 block(NTHR);       // 192 threads = 3 waves
    bert_lattice_pool_kernel<<<grid, block, 0, stream>>>(hidden, word_ids, out);
}

// Round 5
// 177.671 us; speedup vs baseline: 1.0133x; 1.0020x over previous
//
#include <hip/hip_runtime.h>
#include <stdint.h>

// BERT lattice embedding: ragged segment mean-pool.
// hidden: [B,S,H] f32, word_ids: [B,S] i32 (non-decreasing per sample),
// out: [B,T,H] f32; out[b,t,:] = mean of hidden[b,s,:] over s with
// word_ids[b,s]==t (zeros if no piece maps to t).
//
// v6: enforce memory-level parallelism with async global->LDS DMA.
// v1-v5 all pinned at ~61 us / 2.1 TB/s; v5 proved (VGPR=48) that the
// compiler collapses register prefetch to ~2 loads in flight. DMA loads have
// no dest registers -> nothing to collapse; counted s_waitcnt vmcnt(N) +
// raw s_barrier keep the next chunk's 24 KB in flight across barriers.
//  - block = 256 threads (4 waves) owns W=20 words of one sample = one
//    contiguous input row range [r0,r1) (word_ids sorted).
//  - LDS double buffer: CH=8 rows x 3 KB = 24 KB per buffer. Per chunk each
//    wave issues 6 x global_load_lds(16B): rows {2w,2w+1} x 3 segments of
//    1024 B. Steady state: 12 KB in flight per wave, ~144 KB per CU.
//  - consume: thread tid owns cols {tid, tid+256, tid+512}; LDS reads are
//    64 consecutive dwords per wave = 2 lanes/bank (free). Boundary logic is
//    block-uniform registers; scatter-scan bounds (verified in v5).

#define BB 64
#define SS 512
#define HH 768
#define TT 400
#define W   20             // words per block; TT % W == 0
#define WGB (TT / W)       // blocks per sample = 20
#define CH  8              // rows per chunk (24 DMA issues = 4 waves x 6)

__device__ __forceinline__ void dma16(const float* g, const float* l) {
    __builtin_amdgcn_global_load_lds(
        (const __attribute__((address_space(1))) void*)(uintptr_t)g,
        (__attribute__((address_space(3))) void*)(uint32_t)(uintptr_t)l,
        16 /*bytes, literal*/, 0, 0);
}

__global__ __launch_bounds__(256) void bert_lattice_pool_kernel(
    const float* __restrict__ hidden,
    const int* __restrict__ word_ids,
    float* __restrict__ out)
{
    const int blk = blockIdx.x;
    const int b   = blk / WGB;
    const int w0  = (blk - b * WGB) * W;

    __shared__ float s_rows[2 * CH * HH];   // 48 KB double buffer
    __shared__ int   s_w[SS];
    __shared__ int   s_bnd[W + 1];

    const int tid  = threadIdx.x;
    const int wv   = tid >> 6;      // wave 0..3
    const int lane = tid & 63;

    // ---- prologue: stage word_ids row, scatter lower bounds (as v5) ----
    const int2* wrow2 = reinterpret_cast<const int2*>(word_ids + b * SS);
    reinterpret_cast<int2*>(s_w)[tid] = wrow2[tid];      // 256 int2 = 512 ints
    if (tid <= W) s_bnd[tid] = SS;
    __syncthreads();

    for (int s = tid; s < SS; s += 256) {
        const int w  = s_w[s];
        const int wp = (s == 0) ? -1 : s_w[s - 1];
        int lo = wp + 1; if (lo < w0) lo = w0;
        int hi = w;      if (hi > w0 + W) hi = w0 + W;
        for (int t = lo; t <= hi; ++t) s_bnd[t - w0] = s;
    }
    __syncthreads();

    const int r0 = s_bnd[0];
    const int r1 = s_bnd[W];

    float* outp = out + (size_t)b * TT * HH;   // + (w0+t)*HH + col

#define ZWORD(tt) do {                                                \
        float* o_ = outp + (size_t)(w0 + (tt)) * HH + tid;            \
        o_[0] = 0.f; o_[256] = 0.f; o_[512] = 0.f;                    \
    } while (0)

    if (r0 >= r1) {                 // whole block empty (block-uniform)
        for (int t = 0; t < W; ++t) ZWORD(t);
        return;
    }

    // Flush leading zero-piece words.
    int t = 0;
    while (t < W && s_bnd[t + 1] == r0) { ZWORD(t); ++t; }

    int ws = r0;                               // current word's start row
    int e  = (t < W) ? s_bnd[t + 1] : -1;      // current word's end row
    float a0 = 0.f, a1 = 0.f, a2 = 0.f;

    const int rmax = r1 - 1;
    const int nch  = (r1 - r0 + CH - 1) / CH;
    const float* hsrc = hidden + (size_t)b * SS * HH;

    // Per chunk, this wave DMAs rows {2*wv, 2*wv+1} x segments {0,1,2}.
    auto STAGE = [&](int c) {
        const int cbase = r0 + c * CH;
        const float* lb = s_rows + (c & 1) * (CH * HH);
        #pragma unroll
        for (int k = 0; k < 6; ++k) {
            const int rrow = wv * 2 + k / 3;        // k/3, k%3 compile-time
            const int seg  = (k % 3) * 256;
            int rr = cbase + rrow;
            rr = rr > rmax ? rmax : rr;             // clamp: no OOB, no branch
            dma16(hsrc + (size_t)rr * HH + seg + lane * 4,
                  lb + rrow * HH + seg);            // wave-uniform LDS base
        }
    };

    STAGE(0);
    if (nch > 1) STAGE(1);

    for (int c = 0; c < nch; ++c) {
        // Wait for chunk c's DMA (6 per wave); keep chunk c+1 in flight.
        if (c + 1 < nch) { asm volatile("s_waitcnt vmcnt(6)" ::: "memory"); }
        else             { asm volatile("s_waitcnt vmcnt(0)" ::: "memory"); }
        __builtin_amdgcn_sched_barrier(0);
        __builtin_amdgcn_s_barrier();      // all waves' chunk-c data in LDS
        __builtin_amdgcn_sched_barrier(0);

        const int cbase = r0 + c * CH;
        const float* lb = s_rows + (c & 1) * (CH * HH) + tid;
        #pragma unroll
        for (int i = 0; i < CH; ++i) {
            const int r = cbase + i;
            if (r < r1) {                            // block-uniform
                a0 += lb[i * HH];
                a1 += lb[i * HH + 256];
                a2 += lb[i * HH + 512];
                if (r + 1 == e) {                    // word boundary
                    const float inv = 1.0f / (float)(e - ws);
                    float* o = outp + (size_t)(w0 + t) * HH + tid;
                    o[0] = a0 * inv; o[256] = a1 * inv; o[512] = a2 * inv;
                    a0 = a1 = a2 = 0.f; ws = e; ++t;
                    while (t < W && s_bnd[t + 1] == e) { ZWORD(t); ++t; }
                    e = (t < W) ? s_bnd[t + 1] : -1;
                }
            }
        }

        __builtin_amdgcn_sched_barrier(0);
        __builtin_amdgcn_s_barrier();      // all waves done reading buf (c&1)
        __builtin_amdgcn_sched_barrier(0);
        if (c + 2 < nch) STAGE(c + 2);     // refill the just-freed buffer
    }
#undef ZWORD
}

extern "C" void kernel_launch(void* const* d_in, const int* in_sizes, int n_in,
                              void* d_out, int out_size, void* d_ws, size_t ws_size,
                              hipStream_t stream) {
    (void)in_sizes; (void)n_in; (void)d_ws; (void)ws_size; (void)out_size;
    const float* hidden   = (const float*)d_in[0];
    const int*   word_ids = (const int*)d_in[1];
    float*       out      = (float*)d_out;

    dim3 grid(BB * WGB);   // 1280 blocks
    dim3 block(256);       // 4 waves
    bert_lattice_pool_kernel<<<grid, block, 0, stream>>>(hidden, word_ids, out);
}

// Round 6
// 176.132 us; speedup vs baseline: 1.0221x; 1.0087x over previous
//
#include <hip/hip_runtime.h>

// BERT lattice embedding: ragged segment mean-pool.
// hidden: [B,S,H] f32, word_ids: [B,S] i32 (non-decreasing per sample),
// out: [B,T,H] f32; out[b,t,:] = mean of hidden[b,s,:] over s with
// word_ids[b,s]==t (zeros if no piece maps to t).
//
// v7: amputate the per-wave prologue. v1-v6 all pinned at ~60 us; v6 proved
// (DMA-enforced depth) that per-wave MLP is not the limiter. The surviving
// invariant is the dependent bounds-resolution chain every wave executes
// before its first streaming load (9 serial cached reads, or LDS stage +
// barriers). Little's law on v1 gives ~9 us wave lifetime vs ~0.3 us of
// streaming work -> waves live in prologue latency. fillBuffer hits 85% BW
// at 9% occupancy with ZERO prologue.
//  - Kernel A (64 blocks, ~3 us): per sample, scatter-scan lower bounds
//    L[b][t] (t=0..400, L[400]=512 sentinel) in LDS, write to workspace.
//  - Kernel B: v1's pure streaming body. 4 independent waves per block
//    (no LDS, no barriers, ~20 VGPR -> full occupancy). Each wave: ONE
//    dependent 8 B bounds load, then stream rows (3x float4/lane, fully
//    coalesced) and store. cnt==0 words naturally write zeros.

#include <stdint.h>

#define BB 64
#define SS 512
#define HH 768
#define TT 400
#define LN (TT + 1)        // bounds per sample (incl. sentinel)
#define NF4 (HH / 4)       // 192 float4 per row

// ---- Kernel A: per-sample lower bounds into workspace ----
__global__ __launch_bounds__(256) void bounds_kernel(
    const int* __restrict__ word_ids, int* __restrict__ L)
{
    const int b   = blockIdx.x;
    const int tid = threadIdx.x;

    __shared__ int s_w[SS];
    __shared__ int s_L[LN];

    const int2* r2 = reinterpret_cast<const int2*>(word_ids + b * SS);
    reinterpret_cast<int2*>(s_w)[tid] = r2[tid];          // 512 ints
    for (int t = tid; t < LN; t += 256) s_L[t] = SS;      // sentinel fill
    __syncthreads();

    // For each s: words t with w[s-1] < t <= w[s] have lower_bound(t) == s.
    // Ranges are disjoint across s -> race-free LDS writes.
    for (int s = tid; s < SS; s += 256) {
        const int w  = s_w[s];
        const int wp = (s == 0) ? -1 : s_w[s - 1];
        for (int t = wp + 1; t <= w; ++t) s_L[t] = s;
    }
    __syncthreads();

    int* Lb = L + b * LN;
    for (int t = tid; t < LN; t += 256) Lb[t] = s_L[t];   // coalesced
}

// ---- Kernel B: pure streaming pool, 4 independent waves per block ----
__global__ __launch_bounds__(256) void bert_lattice_pool_kernel(
    const float* __restrict__ hidden,
    const int* __restrict__ L,
    float* __restrict__ out)
{
    const int blk  = blockIdx.x;            // 0 .. BB*TT/4-1
    const int b    = blk / (TT / 4);        // /100
    const int q    = blk - b * (TT / 4);
    const int wv   = threadIdx.x >> 6;      // wave 0..3, fully independent
    const int lane = threadIdx.x & 63;
    const int t    = q * 4 + wv;

    // One dependent hop: 8 B of bounds (same line for all lanes of the wave).
    const int* Lb   = L + b * LN + t;
    const int start = Lb[0];
    const int end   = Lb[1];
    const int count = end - start;

    const float4* hp = reinterpret_cast<const float4*>(hidden)
                       + (size_t)(b * SS) * NF4;

    float4 a0 = make_float4(0.f, 0.f, 0.f, 0.f);
    float4 a1 = a0, a2 = a0;

    for (int s = start; s < end; ++s) {
        const float4* p = hp + (size_t)s * NF4;
        float4 v0 = p[lane];
        float4 v1 = p[lane + 64];
        float4 v2 = p[lane + 128];
        a0.x += v0.x; a0.y += v0.y; a0.z += v0.z; a0.w += v0.w;
        a1.x += v1.x; a1.y += v1.y; a1.z += v1.z; a1.w += v1.w;
        a2.x += v2.x; a2.y += v2.y; a2.z += v2.z; a2.w += v2.w;
    }

    const float inv = 1.0f / (float)(count > 0 ? count : 1);

    float4* o = reinterpret_cast<float4*>(out) + ((size_t)b * TT + t) * NF4;
    o[lane]       = make_float4(a0.x * inv, a0.y * inv, a0.z * inv, a0.w * inv);
    o[lane + 64]  = make_float4(a1.x * inv, a1.y * inv, a1.z * inv, a1.w * inv);
    o[lane + 128] = make_float4(a2.x * inv, a2.y * inv, a2.z * inv, a2.w * inv);
}

extern "C" void kernel_launch(void* const* d_in, const int* in_sizes, int n_in,
                              void* d_out, int out_size, void* d_ws, size_t ws_size,
                              hipStream_t stream) {
    (void)in_sizes; (void)n_in; (void)ws_size; (void)out_size;
    const float* hidden   = (const float*)d_in[0];
    const int*   word_ids = (const int*)d_in[1];
    float*       out      = (float*)d_out;
    int*         L        = (int*)d_ws;     // BB*LN ints = 102.7 KB

    bounds_kernel<<<dim3(BB), dim3(256), 0, stream>>>(word_ids, L);

    // 4 words per block (one per wave), BB*TT/4 = 6400 blocks.
    bert_lattice_pool_kernel<<<dim3(BB * TT / 4), dim3(256), 0, stream>>>(
        hidden, L, out);
}

// Round 8
// 174.166 us; speedup vs baseline: 1.0337x; 1.0113x over previous
//
#include <hip/hip_runtime.h>
#include <stdint.h>

// BERT lattice embedding: ragged segment mean-pool.
// hidden: [B,S,H] f32, word_ids: [B,S] i32 (non-decreasing per sample),
// out: [B,T,H] f32; out[b,t,:] = mean of hidden[b,s,:] over s with
// word_ids[b,s]==t (zeros if no piece maps to t).
//
// v9 == v8 with the compile fix: __builtin_nontemporal_* requires clang
// vector types, not HIP_vector_type (float4). Uses ext_vector_type(4).
//  - NONTEMPORAL loads+stores: zero intra-iteration reuse, so every cache
//    allocation is pollution; nt hints shorten the miss/evict path and give
//    DRAM clean streams (the property the 86%-BW fillBuffer enjoys).
//  - persistent waves, zero tail: 1600 blocks x 4 waves (25 waves/CU),
//    exactly 2 jobs per block; each wave pools TWO adjacent words per job,
//    whose pieces form ONE contiguous row range [L[t], L[t+2]).
// Kernel A (bounds precompute, verified in v7) unchanged.

#define BB 64
#define SS 512
#define HH 768
#define TT 400
#define LN (TT + 1)        // bounds per sample (incl. sentinel)
#define NF4 (HH / 4)       // 192 float4 per row
#define JPB (TT / 8)       // jobs per sample = 50 (8 words per job)
#define NJ  (BB * JPB)     // 3200 jobs
#define GRID 1600          // NJ / GRID == 2 jobs per block exactly

typedef float f4 __attribute__((ext_vector_type(4)));

// ---- Kernel A: per-sample lower bounds into workspace ----
__global__ __launch_bounds__(256) void bounds_kernel(
    const int* __restrict__ word_ids, int* __restrict__ L)
{
    const int b   = blockIdx.x;
    const int tid = threadIdx.x;

    __shared__ int s_w[SS];
    __shared__ int s_L[LN];

    const int2* r2 = reinterpret_cast<const int2*>(word_ids + b * SS);
    reinterpret_cast<int2*>(s_w)[tid] = r2[tid];          // 512 ints
    for (int t = tid; t < LN; t += 256) s_L[t] = SS;      // sentinel fill
    __syncthreads();

    // For each s: words t with w[s-1] < t <= w[s] have lower_bound(t) == s.
    // Ranges disjoint across s -> race-free LDS writes.
    for (int s = tid; s < SS; s += 256) {
        const int w  = s_w[s];
        const int wp = (s == 0) ? -1 : s_w[s - 1];
        for (int t = wp + 1; t <= w; ++t) s_L[t] = s;
    }
    __syncthreads();

    int* Lb = L + b * LN;
    for (int t = tid; t < LN; t += 256) Lb[t] = s_L[t];   // coalesced
}

// ---- Kernel B: persistent streaming pool, nontemporal, 2 words/wave ----
__global__ __launch_bounds__(256) void bert_lattice_pool_kernel(
    const float* __restrict__ hidden,
    const int* __restrict__ L,
    float* __restrict__ out)
{
    const int wv   = threadIdx.x >> 6;   // wave 0..3 (independent)
    const int lane = threadIdx.x & 63;
    const f4 z4 = {0.f, 0.f, 0.f, 0.f};

    for (int job = blockIdx.x; job < NJ; job += GRID) {
        const int b  = job / JPB;
        const int t0 = (job - b * JPB) * 8 + wv * 2;   // this wave: t0, t0+1

        // Wave-uniform bounds: contiguous row range [s0, e1), split at e0.
        const int* Lb = L + b * LN + t0;
        const int s0 = Lb[0];
        const int e0 = Lb[1];
        const int e1 = Lb[2];

        const f4* hp = reinterpret_cast<const f4*>(hidden)
                       + (size_t)(b * SS) * NF4;

        f4 p0 = z4, p1 = z4, p2 = z4;    // word t0 accumulators
        f4 q0 = z4, q1 = z4, q2 = z4;    // word t0+1 accumulators

        for (int s = s0; s < e1; ++s) {
            const f4* p = hp + (size_t)s * NF4;
            const f4 v0 = __builtin_nontemporal_load(p + lane);
            const f4 v1 = __builtin_nontemporal_load(p + lane + 64);
            const f4 v2 = __builtin_nontemporal_load(p + lane + 128);
            if (s < e0) {   // wave-uniform branch
                p0 += v0; p1 += v1; p2 += v2;
            } else {
                q0 += v0; q1 += v1; q2 += v2;
            }
        }

        const int   c0 = e0 - s0;
        const int   c1 = e1 - e0;
        const float i0 = 1.0f / (float)(c0 > 0 ? c0 : 1);
        const float i1 = 1.0f / (float)(c1 > 0 ? c1 : 1);

        f4* o0 = reinterpret_cast<f4*>(out) + ((size_t)b * TT + t0) * NF4;
        f4* o1 = o0 + NF4;

        __builtin_nontemporal_store(p0 * i0, o0 + lane);
        __builtin_nontemporal_store(p1 * i0, o0 + lane + 64);
        __builtin_nontemporal_store(p2 * i0, o0 + lane + 128);
        __builtin_nontemporal_store(q0 * i1, o1 + lane);
        __builtin_nontemporal_store(q1 * i1, o1 + lane + 64);
        __builtin_nontemporal_store(q2 * i1, o1 + lane + 128);
    }
}

extern "C" void kernel_launch(void* const* d_in, const int* in_sizes, int n_in,
                              void* d_out, int out_size, void* d_ws, size_t ws_size,
                              hipStream_t stream) {
    (void)in_sizes; (void)n_in; (void)ws_size; (void)out_size;
    const float* hidden   = (const float*)d_in[0];
    const int*   word_ids = (const int*)d_in[1];
    float*       out      = (float*)d_out;
    int*         L        = (int*)d_ws;     // BB*LN ints = 102.7 KB

    bounds_kernel<<<dim3(BB), dim3(256), 0, stream>>>(word_ids, L);
    bert_lattice_pool_kernel<<<dim3(GRID), dim3(256), 0, stream>>>(
        hidden, L, out);
}

// Round 9
// 170.702 us; speedup vs baseline: 1.0546x; 1.0203x over previous
//
#include <hip/hip_runtime.h>
#include <stdint.h>

// BERT lattice embedding: ragged segment mean-pool.
// hidden: [B,S,H] f32, word_ids: [B,S] i32 (non-decreasing per sample),
// out: [B,T,H] f32; out[b,t,:] = mean of hidden[b,s,:] over s with
// word_ids[b,s]==t (zeros if no piece maps to t).
//
// v10: stream-locality experiment (last untested mechanism).
//  - XCD-contiguous block remap q=(p%8)*200+p/8 (bijective, 1600=8x200):
//    each XCD's 200 blocks cover a CONTIGUOUS ~12.6 MB slab of hidden/out
//    instead of a stride-8 interleave -> DRAM page/bank locality + per-XCD
//    L2 locality (T1 analog; +10% on HBM-bound GEMM).
//  - one-shot waves: 4 words per wave (16 per block), no grid-stride loop.
//  - 2-row unrolled inner loop: 6 independent nt loads per burst in one
//    basic block (2x per-wave bytes in flight vs v9).
//  - wave-uniform word tracking with NAMED accumulators (switch on t;
//    no runtime-indexed register arrays -> no scratch). Empty words write
//    zeros naturally (their acc is never touched).
//  - nontemporal loads+stores kept from v9 (best so far).
// Kernel A (bounds precompute, verified since v7) unchanged.

#define BB 64
#define SS 512
#define HH 768
#define TT 400
#define LN (TT + 1)        // bounds per sample (incl. sentinel)
#define NF4 (HH / 4)       // 192 float4 per row
#define WPW 4              // words per wave
#define WPB 16             // words per block (4 waves)
#define CPS (TT / WPB)     // word-chunks per sample = 25
#define NBLK (BB * CPS)    // 1600 blocks
#define NXCD 8
#define BPX (NBLK / NXCD)  // 200 blocks per XCD slab

typedef float f4 __attribute__((ext_vector_type(4)));

// ---- Kernel A: per-sample lower bounds into workspace ----
__global__ __launch_bounds__(256) void bounds_kernel(
    const int* __restrict__ word_ids, int* __restrict__ L)
{
    const int b   = blockIdx.x;
    const int tid = threadIdx.x;

    __shared__ int s_w[SS];
    __shared__ int s_L[LN];

    const int2* r2 = reinterpret_cast<const int2*>(word_ids + b * SS);
    reinterpret_cast<int2*>(s_w)[tid] = r2[tid];          // 512 ints
    for (int t = tid; t < LN; t += 256) s_L[t] = SS;      // sentinel fill
    __syncthreads();

    // For each s: words t with w[s-1] < t <= w[s] have lower_bound(t) == s.
    // Ranges disjoint across s -> race-free LDS writes.
    for (int s = tid; s < SS; s += 256) {
        const int w  = s_w[s];
        const int wp = (s == 0) ? -1 : s_w[s - 1];
        for (int t = wp + 1; t <= w; ++t) s_L[t] = s;
    }
    __syncthreads();

    int* Lb = L + b * LN;
    for (int t = tid; t < LN; t += 256) Lb[t] = s_L[t];   // coalesced
}

// ---- Kernel B: XCD-slabbed streaming pool, 4 words per wave ----
__global__ __launch_bounds__(256) void bert_lattice_pool_kernel(
    const float* __restrict__ hidden,
    const int* __restrict__ L,
    float* __restrict__ out)
{
    const int p  = blockIdx.x;
    const int q  = (p % NXCD) * BPX + p / NXCD;   // xcd-contiguous remap
    const int b  = q / CPS;
    const int w0 = (q - b * CPS) * WPB + (threadIdx.x >> 6) * WPW;
    const int lane = threadIdx.x & 63;

    // Wave-uniform bounds for words w0..w0+3 (contiguous rows [b0, b4)).
    const int* Lb = L + b * LN + w0;
    const int b0 = Lb[0], b1 = Lb[1], b2 = Lb[2], b3 = Lb[3], b4 = Lb[4];

    const f4* hp = reinterpret_cast<const f4*>(hidden)
                   + (size_t)(b * SS) * NF4 + lane;

    const f4 z4 = {0.f, 0.f, 0.f, 0.f};
    f4 a00 = z4, a01 = z4, a02 = z4;   // word w0
    f4 a10 = z4, a11 = z4, a12 = z4;   // word w0+1
    f4 a20 = z4, a21 = z4, a22 = z4;   // word w0+2
    f4 a30 = z4, a31 = z4, a32 = z4;   // word w0+3

    int s = b0;
    const int send = b4;
    const int smax = send - 1;
    int t = 0;          // current word (wave-uniform, only increases)
    int e = b1;         // end row of current word

#define ADD_ROW(V0, V1, V2, SR)                                        \
    do {                                                               \
        while ((SR) >= e) { ++t; e = (t == 1) ? b2 : (t == 2) ? b3 : b4; } \
        switch (t) {                                                   \
            case 0: a00 += (V0); a01 += (V1); a02 += (V2); break;      \
            case 1: a10 += (V0); a11 += (V1); a12 += (V2); break;      \
            case 2: a20 += (V0); a21 += (V1); a22 += (V2); break;      \
            default: a30 += (V0); a31 += (V1); a32 += (V2); break;     \
        }                                                              \
    } while (0)

    while (s < send) {
        const int s1c = (s + 1 > smax) ? smax : s + 1;   // clamped (in-bounds)
        const f4* p0 = hp + (size_t)s * NF4;
        const f4* p1 = hp + (size_t)s1c * NF4;
        // 6 independent nontemporal loads in one basic block.
        const f4 u0 = __builtin_nontemporal_load(p0);
        const f4 u1 = __builtin_nontemporal_load(p0 + 64);
        const f4 u2 = __builtin_nontemporal_load(p0 + 128);
        const f4 v0 = __builtin_nontemporal_load(p1);
        const f4 v1 = __builtin_nontemporal_load(p1 + 64);
        const f4 v2 = __builtin_nontemporal_load(p1 + 128);

        ADD_ROW(u0, u1, u2, s);
        if (s + 1 < send) ADD_ROW(v0, v1, v2, s + 1);
        s += 2;
    }
#undef ADD_ROW

    // Epilogue: means (empty words have zero acc; inv over max(cnt,1)).
    f4* o = reinterpret_cast<f4*>(out) + ((size_t)b * TT + w0) * NF4 + lane;
    {
        const int c = b1 - b0; const float inv = 1.0f / (float)(c > 0 ? c : 1);
        __builtin_nontemporal_store(a00 * inv, o);
        __builtin_nontemporal_store(a01 * inv, o + 64);
        __builtin_nontemporal_store(a02 * inv, o + 128);
    }
    o += NF4;
    {
        const int c = b2 - b1; const float inv = 1.0f / (float)(c > 0 ? c : 1);
        __builtin_nontemporal_store(a10 * inv, o);
        __builtin_nontemporal_store(a11 * inv, o + 64);
        __builtin_nontemporal_store(a12 * inv, o + 128);
    }
    o += NF4;
    {
        const int c = b3 - b2; const float inv = 1.0f / (float)(c > 0 ? c : 1);
        __builtin_nontemporal_store(a20 * inv, o);
        __builtin_nontemporal_store(a21 * inv, o + 64);
        __builtin_nontemporal_store(a22 * inv, o + 128);
    }
    o += NF4;
    {
        const int c = b4 - b3; const float inv = 1.0f / (float)(c > 0 ? c : 1);
        __builtin_nontemporal_store(a30 * inv, o);
        __builtin_nontemporal_store(a31 * inv, o + 64);
        __builtin_nontemporal_store(a32 * inv, o + 128);
    }
}

extern "C" void kernel_launch(void* const* d_in, const int* in_sizes, int n_in,
                              void* d_out, int out_size, void* d_ws, size_t ws_size,
                              hipStream_t stream) {
    (void)in_sizes; (void)n_in; (void)ws_size; (void)out_size;
    const float* hidden   = (const float*)d_in[0];
    const int*   word_ids = (const int*)d_in[1];
    float*       out      = (float*)d_out;
    int*         L        = (int*)d_ws;     // BB*LN ints = 102.7 KB

    bounds_kernel<<<dim3(BB), dim3(256), 0, stream>>>(word_ids, L);
    bert_lattice_pool_kernel<<<dim3(NBLK), dim3(256), 0, stream>>>(
        hidden, L, out);
}